// Round 1
// baseline (458.034 us; speedup 1.0000x reference)
//
#include <hip/hip_runtime.h>

// Subtractor50Bit: A - B via two's complement, N rows x 50 bits ({0,1} floats).
// out = [result (N*50 floats), borrow (N floats)].
//
// R2: widen everything to 8B/lane. Rows are 50 = 2*25 bits, so every row
// starts at an even element: float2 loads + per-component ballots produce
// clean even/odd bit-PLANES where row r owns the contiguous window
// [25r, 25r+25) of each plane. Per-lane row assembly = 8 shfl64 + shifts +
// two 25->50 Morton spreads per operand pair. Stores are packed 8B
// (a float2 never straddles a row) and nontemporal so the 204MB write
// stream stops evicting A/B from L3.
// VMEM instrs/wave: 151 -> 76 at 2x width; DS ~108 -> ~66.

constexpr int BITS = 50;
constexpr unsigned long long MASK50 = (1ULL << BITS) - 1ULL;

__device__ inline unsigned long long shfl64(unsigned long long v, int src) {
    int lo = __shfl((int)(unsigned)(v & 0xffffffffULL), src, 64);
    int hi = __shfl((int)(unsigned)(v >> 32), src, 64);
    return ((unsigned long long)(unsigned)hi << 32) | (unsigned long long)(unsigned)lo;
}

// bit i -> bit 2i (valid for i < 32)
__device__ inline unsigned long long spread2(unsigned long long x) {
    x = (x | (x << 16)) & 0x0000FFFF0000FFFFULL;
    x = (x | (x << 8))  & 0x00FF00FF00FF00FFULL;
    x = (x | (x << 4))  & 0x0F0F0F0F0F0F0F0FULL;
    x = (x | (x << 2))  & 0x3333333333333333ULL;
    x = (x | (x << 1))  & 0x5555555555555555ULL;
    return x;
}

__global__ __launch_bounds__(256) void Subtractor50Bit_kernel(
    const float* __restrict__ A, const float* __restrict__ B,
    float* __restrict__ out, int N)
{
    const int lane = threadIdx.x & 63;
    const int wv   = threadIdx.x >> 6;
    const long long waveIdx = (long long)blockIdx.x * 4 + wv;
    const long long rowBase = waveIdx * 64;
    if (rowBase >= N) return;

    if (rowBase + 64 <= N) {
        // ---- full-wave fast path (64 rows, all lanes active) ----
        const long long eBase = rowBase * BITS;          // 3200 elements/wave
        const float2* pa = (const float2*)(A + eBase) + lane;
        const float2* pb = (const float2*)(B + eBase) + lane;

        // Phase 1: ALL loads issued first (independent, 512B/instr coalesced).
        float2 fa[25], fb[25];
        #pragma unroll
        for (int t = 0; t < 25; ++t) fa[t] = pa[t * 64];
        #pragma unroll
        for (int t = 0; t < 25; ++t) fb[t] = pb[t * 64];

        // Phase 2: ballots. Chunk t covers elements [128t, 128t+128):
        //   .x ballot = even-plane word t  (bit i = element 128t+2i)
        //   .y ballot = odd-plane  word t  (bit i = element 128t+2i+1)
        // E-words parked in lanes 0..24, O-words in lanes 32..56; others 0.
        unsigned long long wa = 0, wb = 0;
        const int  lane31 = lane & 31;
        const bool isLo   = lane < 32;
        #pragma unroll
        for (int t = 0; t < 25; ++t) {
            unsigned long long aE = __ballot(fa[t].x != 0.0f);
            unsigned long long aO = __ballot(fa[t].y != 0.0f);
            unsigned long long bE = __ballot(fb[t].x != 0.0f);
            unsigned long long bO = __ballot(fb[t].y != 0.0f);
            if (lane31 == t) {
                wa = isLo ? aE : aO;
                wb = isLo ? bE : bO;
            }
        }

        // Phase 3: per-lane row assembly; lane owns row (rowBase + lane).
        // Row's even bits = even-plane window [25*lane, 25*lane+25).
        const int p0 = 25 * lane;
        const int w0 = p0 >> 6;
        const int sh = p0 & 63;

        unsigned long long aE0 = shfl64(wa, w0);
        unsigned long long aE1 = shfl64(wa, w0 + 1);      // lane>56 sources hold 0 (safe)
        unsigned long long aO0 = shfl64(wa, 32 + w0);
        unsigned long long aO1 = shfl64(wa, 33 + w0);
        unsigned long long bE0 = shfl64(wb, w0);
        unsigned long long bE1 = shfl64(wb, w0 + 1);
        unsigned long long bO0 = shfl64(wb, 32 + w0);
        unsigned long long bO1 = shfl64(wb, 33 + w0);

        unsigned long long evA = aE0 >> sh, odA = aO0 >> sh;
        unsigned long long evB = bE0 >> sh, odB = bO0 >> sh;
        if (sh > 39) {               // window straddles two plane words
            const int c = 64 - sh;   // in [1,24] here -> shifts well-defined
            evA |= aE1 << c; odA |= aO1 << c;
            evB |= bE1 << c; odB |= bO1 << c;
        }
        const unsigned long long M25 = (1ULL << 25) - 1ULL;
        evA &= M25; odA &= M25; evB &= M25; odB &= M25;

        unsigned long long av = spread2(evA) | (spread2(odA) << 1);
        unsigned long long bv = spread2(evB) | (spread2(odB) << 1);

        unsigned long long diff = (av - bv) & MASK50;     // A + ~B + 1 (mod 2^50)
        float borrow = (av < bv) ? 1.0f : 0.0f;           // 1 - carry_out

        // Phase 4: packed 8B stores, coalesced 512B/instr. float2 q covers
        // elements [2q, 2q+2) which always lie in ONE row (50 is even).
        unsigned long long* po = (unsigned long long*)(out + eBase);
        #pragma unroll
        for (int j = 0; j < 25; ++j) {
            int q = j * 64 + lane;            // float2 index in [0,1600)
            int r = q / 25;                   // owning local row (magic-mul)
            int k = 2 * (q - r * 25);         // bit index within row
            unsigned long long dr = shfl64(diff, r);
            unsigned long long t2 = dr >> k;
            unsigned long long o =
                  ((t2 & 1ULL) ? 0x000000003F800000ULL : 0ULL)
                | ((t2 & 2ULL) ? 0x3F80000000000000ULL : 0ULL);
            __builtin_nontemporal_store(o, po + q);
        }
        // borrow segment: naturally coalesced
        __builtin_nontemporal_store(borrow, out + (long long)N * BITS + rowBase + lane);
    } else {
        // ---- scalar tail path (partial wave; N%64!=0 safety net) ----
        long long r = rowBase + lane;
        if (r < N) {
            unsigned long long av = 0, bv = 0;
            for (int k = 0; k < BITS; ++k) {
                av |= (unsigned long long)(A[r * BITS + k] != 0.0f) << k;
                bv |= (unsigned long long)(B[r * BITS + k] != 0.0f) << k;
            }
            unsigned long long diff = (av - bv) & MASK50;
            for (int k = 0; k < BITS; ++k)
                out[r * BITS + k] = (float)((diff >> k) & 1ULL);
            out[(long long)N * BITS + r] = (av < bv) ? 1.0f : 0.0f;
        }
    }
}

extern "C" void kernel_launch(void* const* d_in, const int* in_sizes, int n_in,
                              void* d_out, int out_size, void* d_ws, size_t ws_size,
                              hipStream_t stream) {
    const float* A = (const float*)d_in[0];
    const float* B = (const float*)d_in[1];
    float* out = (float*)d_out;
    const int N = in_sizes[0] / BITS;          // 1,000,000

    const int waves  = (N + 63) / 64;          // one wave per 64 rows
    const int blocks = (waves + 3) / 4;        // 4 waves per 256-thread block
    Subtractor50Bit_kernel<<<blocks, 256, 0, stream>>>(A, B, out, N);
}

// Round 2
// 447.764 us; speedup vs baseline: 1.0229x; 1.0229x over previous
//
#include <hip/hip_runtime.h>

// Subtractor50Bit: A - B via two's complement, N rows x 50 bits ({0,1} floats).
// out = [result (N*50 floats), borrow (N floats)].
//
// R3: same float2/bit-plane structure as R2, but FORCE the load window.
// R2's regression (156->173us) was the register allocator sinking the 50
// "phase-split" float2 loads into the ballot loop (VGPR 56->36, ~4 loads in
// flight -> per-ballot HBM-latency stalls). sched_barrier(0) after the load
// loops forbids any instruction from crossing: all 50 loads (25.6KB/wave,
// 512B/instr coalesced) must be issued and live before the first ballot.
// Expected VGPR ~120-130, occupancy ~16 waves/CU -- ~400KB/CU in flight vs
// ~10KB needed to cover HBM latency at full BW.
// Also reverts R2's nontemporal stores (zero FETCH_SIZE effect, store-path
// regression suspect).

constexpr int BITS = 50;
constexpr unsigned long long MASK50 = (1ULL << BITS) - 1ULL;

__device__ inline unsigned long long shfl64(unsigned long long v, int src) {
    int lo = __shfl((int)(unsigned)(v & 0xffffffffULL), src, 64);
    int hi = __shfl((int)(unsigned)(v >> 32), src, 64);
    return ((unsigned long long)(unsigned)hi << 32) | (unsigned long long)(unsigned)lo;
}

// bit i -> bit 2i (valid for i < 32)
__device__ inline unsigned long long spread2(unsigned long long x) {
    x = (x | (x << 16)) & 0x0000FFFF0000FFFFULL;
    x = (x | (x << 8))  & 0x00FF00FF00FF00FFULL;
    x = (x | (x << 4))  & 0x0F0F0F0F0F0F0F0FULL;
    x = (x | (x << 2))  & 0x3333333333333333ULL;
    x = (x | (x << 1))  & 0x5555555555555555ULL;
    return x;
}

__global__ __launch_bounds__(256) void Subtractor50Bit_kernel(
    const float* __restrict__ A, const float* __restrict__ B,
    float* __restrict__ out, int N)
{
    const int lane = threadIdx.x & 63;
    const int wv   = threadIdx.x >> 6;
    const long long waveIdx = (long long)blockIdx.x * 4 + wv;
    const long long rowBase = waveIdx * 64;
    if (rowBase >= N) return;

    if (rowBase + 64 <= N) {
        // ---- full-wave fast path (64 rows, all lanes active) ----
        const long long eBase = rowBase * BITS;          // 3200 elements/wave
        const float2* pa = (const float2*)(A + eBase) + lane;
        const float2* pb = (const float2*)(B + eBase) + lane;

        // Phase 1: ALL loads issued first (independent, 512B/instr coalesced).
        float2 fa[25], fb[25];
        #pragma unroll
        for (int t = 0; t < 25; ++t) fa[t] = pa[t * 64];
        #pragma unroll
        for (int t = 0; t < 25; ++t) fb[t] = pb[t * 64];

        // Hard fence: nothing may cross. Loads cannot sink into the ballot
        // loop; the full 50-load window stays in flight (forces ~100 live
        // VGPRs -- that is the point).
        __builtin_amdgcn_sched_barrier(0);

        // Phase 2: ballots. Chunk t covers elements [128t, 128t+128):
        //   .x ballot = even-plane word t  (bit i = element 128t+2i)
        //   .y ballot = odd-plane  word t  (bit i = element 128t+2i+1)
        // E-words parked in lanes 0..24, O-words in lanes 32..56; others 0.
        unsigned long long wa = 0, wb = 0;
        const int  lane31 = lane & 31;
        const bool isLo   = lane < 32;
        #pragma unroll
        for (int t = 0; t < 25; ++t) {
            unsigned long long aE = __ballot(fa[t].x != 0.0f);
            unsigned long long aO = __ballot(fa[t].y != 0.0f);
            unsigned long long bE = __ballot(fb[t].x != 0.0f);
            unsigned long long bO = __ballot(fb[t].y != 0.0f);
            if (lane31 == t) {
                wa = isLo ? aE : aO;
                wb = isLo ? bE : bO;
            }
        }

        // Phase 3: per-lane row assembly; lane owns row (rowBase + lane).
        // Row's even bits = even-plane window [25*lane, 25*lane+25).
        const int p0 = 25 * lane;
        const int w0 = p0 >> 6;
        const int sh = p0 & 63;

        unsigned long long aE0 = shfl64(wa, w0);
        unsigned long long aE1 = shfl64(wa, w0 + 1);      // lane>56 sources hold 0 (safe)
        unsigned long long aO0 = shfl64(wa, 32 + w0);
        unsigned long long aO1 = shfl64(wa, 33 + w0);
        unsigned long long bE0 = shfl64(wb, w0);
        unsigned long long bE1 = shfl64(wb, w0 + 1);
        unsigned long long bO0 = shfl64(wb, 32 + w0);
        unsigned long long bO1 = shfl64(wb, 33 + w0);

        unsigned long long evA = aE0 >> sh, odA = aO0 >> sh;
        unsigned long long evB = bE0 >> sh, odB = bO0 >> sh;
        if (sh > 39) {               // window straddles two plane words
            const int c = 64 - sh;   // in [1,24] here -> shifts well-defined
            evA |= aE1 << c; odA |= aO1 << c;
            evB |= bE1 << c; odB |= bO1 << c;
        }
        const unsigned long long M25 = (1ULL << 25) - 1ULL;
        evA &= M25; odA &= M25; evB &= M25; odB &= M25;

        unsigned long long av = spread2(evA) | (spread2(odA) << 1);
        unsigned long long bv = spread2(evB) | (spread2(odB) << 1);

        unsigned long long diff = (av - bv) & MASK50;     // A + ~B + 1 (mod 2^50)
        float borrow = (av < bv) ? 1.0f : 0.0f;           // 1 - carry_out

        // Phase 4: packed 8B stores, coalesced 512B/instr. float2 q covers
        // elements [2q, 2q+2) which always lie in ONE row (50 is even).
        // All 25 bpermute pairs depend only on diff -> compiler pipelines them.
        unsigned long long* po = (unsigned long long*)(out + eBase);
        #pragma unroll
        for (int j = 0; j < 25; ++j) {
            int q = j * 64 + lane;            // float2 index in [0,1600)
            int r = q / 25;                   // owning local row (magic-mul)
            int k = 2 * (q - r * 25);         // bit index within row
            unsigned long long dr = shfl64(diff, r);
            unsigned long long t2 = dr >> k;
            po[q] = ((t2 & 1ULL) ? 0x000000003F800000ULL : 0ULL)
                  | ((t2 & 2ULL) ? 0x3F80000000000000ULL : 0ULL);
        }
        // borrow segment: naturally coalesced
        out[(long long)N * BITS + rowBase + lane] = borrow;
    } else {
        // ---- scalar tail path (partial wave; N%64!=0 safety net) ----
        long long r = rowBase + lane;
        if (r < N) {
            unsigned long long av = 0, bv = 0;
            for (int k = 0; k < BITS; ++k) {
                av |= (unsigned long long)(A[r * BITS + k] != 0.0f) << k;
                bv |= (unsigned long long)(B[r * BITS + k] != 0.0f) << k;
            }
            unsigned long long diff = (av - bv) & MASK50;
            for (int k = 0; k < BITS; ++k)
                out[r * BITS + k] = (float)((diff >> k) & 1ULL);
            out[(long long)N * BITS + r] = (av < bv) ? 1.0f : 0.0f;
        }
    }
}

extern "C" void kernel_launch(void* const* d_in, const int* in_sizes, int n_in,
                              void* d_out, int out_size, void* d_ws, size_t ws_size,
                              hipStream_t stream) {
    const float* A = (const float*)d_in[0];
    const float* B = (const float*)d_in[1];
    float* out = (float*)d_out;
    const int N = in_sizes[0] / BITS;          // 1,000,000

    const int waves  = (N + 63) / 64;          // one wave per 64 rows
    const int blocks = (waves + 3) / 4;        // 4 waves per 256-thread block
    Subtractor50Bit_kernel<<<blocks, 256, 0, stream>>>(A, B, out, N);
}